// Round 13
// baseline (587.086 us; speedup 1.0000x reference)
//
#include <hip/hip_runtime.h>

typedef short short8 __attribute__((ext_vector_type(8)));
typedef float f32x4 __attribute__((ext_vector_type(4)));
typedef unsigned short ushort8_t __attribute__((ext_vector_type(8)));

#define O_CH 128
#define I_CH 128
#define HW 112
#define PLANE (HW * HW)      // 12544
#define NCOLW 34             // per-wave col stride (30 staged + 4 pad-read)
#define SUBB (NCOLW * 64)    // bytes per sub-row = 2176
#define WBUF (3 * SUBB)      // bytes per wave buffer = 6528
#define WREG (2 * WBUF)      // per-wave LDS region = 13056

__device__ __forceinline__ unsigned short f2bf(float f) {
  union { float f; unsigned u; } v; v.f = f;
  unsigned r = v.u + 0x7FFFu + ((v.u >> 16) & 1u);   // RNE (weights only)
  return (unsigned short)(r >> 16);
}

// one-instruction truncate-pack: [lo,hi] floats -> packed bf16 pair
__device__ __forceinline__ unsigned pktrunc(float lo, float hi) {
  union { float f; unsigned u; } a, b; a.f = lo; b.f = hi;
  return __builtin_amdgcn_perm(b.u, a.u, 0x07060302u);
}

__global__ void wsynth_kernel(const float* __restrict__ core,
                              const float* __restrict__ periph,
                              const float* __restrict__ thr,
                              const float* __restrict__ scale,
                              unsigned short* __restrict__ Wb) {
  int idx = blockIdx.x * blockDim.x + threadIdx.x;   // o*128 + i
  if (idx >= O_CH * I_CH) return;
  int o = idx >> 7;
  float c = core[idx];
  float s = scale[0];
  float g = 1.0f / (1.0f + __expf(-s * (fabsf(c) - thr[o])));
#pragma unroll
  for (int tap = 0; tap < 9; ++tap) {
    float p  = (tap == 4) ? 1.0f : periph[tap < 4 ? tap : tap - 1];
    float gg = (tap == 4) ? 1.0f : g;
    Wb[tap * (O_CH * I_CH) + idx] = f2bf(c * p * gg);   // layout [tap][o][i]
  }
}

// Barrier-free conv: 4 independent waves per WG; wave = (col-quarter) x all 128 O.
__global__ __launch_bounds__(256, 3)
void conv_wi(const float* __restrict__ X,
             const unsigned short* __restrict__ Wb,
             float* __restrict__ Out) {
  // per-wave private region: 2 bufs x [3 sub-rows][34 cols][32 ch] bf16,
  // col-row = 64 B = 4 slots of 16 B, slot' = oct ^ ((col>>1)&3) (verified 0-conflict)
  __shared__ __align__(16) unsigned short Xs[4 * WREG / 2];   // 52,224 B -> 3 WGs/CU
  char* lds = (char*)Xs;

  // XCD-chunked swizzle: 3584 = 8 XCDs x 448 (R6-verified)
  const int bid = blockIdx.x;
  const int L = (bid & 7) * 448 + (bid >> 3);
  const int b = L / HW;
  const int y = L - b * HW;

  const int t   = threadIdx.x;
  const int wv  = t >> 6;              // wave 0..3 -> col quarter
  const int l   = t & 63;
  const int ln  = l & 15;              // MFMA frag lane
  const int lk4 = l >> 4;              // k-slice 0..3
  const int cb  = wv * 28;             // output col base

  char* wbase = lds + wv * WREG;       // this wave's private LDS

  // staging: 120 b128 units (30 cols x 4 ch-octs); lane covers u = l and l+64
  const int cu0  = l >> 2;             // unit 0 col (0..15)
  const int oct0 = l & 3;
  const int u1   = l + 64;
  const bool v1  = (u1 < 120);
  const int cu1  = u1 >> 2;            // unit 1 col (16..29)
  const int oct1 = u1 & 3;

  f32x4 acc[8][2];                     // [m-frag][nf]
#pragma unroll
  for (int mt = 0; mt < 8; ++mt)
#pragma unroll
    for (int nf = 0; nf < 2; ++nf)
      acc[mt][nf] = (f32x4)0.0f;

  // ---- stage-load: 16 f32 (2 units x 8 ch) for (chunk K, sub-row SUB) ----
#define SLOAD(V, K, SUB)                                                        \
  {                                                                             \
    const int row_ = y + (SUB)-1;                                               \
    const bool rok_ = (row_ >= 0) && (row_ < HW);                               \
    {                                                                           \
      const int ic_ = cb - 1 + cu0;                                             \
      const bool ok_ = rok_ && (ic_ >= 0) && (ic_ < HW);                        \
      const float* sp_ = X + ((size_t)(b * I_CH + (K)*32 + oct0 * 8) * HW       \
                              + row_) * HW + ic_;                               \
      _Pragma("unroll") for (int j = 0; j < 8; ++j)                             \
        V[j] = ok_ ? sp_[j * PLANE] : 0.0f;                                     \
    }                                                                           \
    {                                                                           \
      const int ic_ = cb - 1 + cu1;                                             \
      const bool ok_ = v1 && rok_ && (ic_ >= 0) && (ic_ < HW);                  \
      const float* sp_ = X + ((size_t)(b * I_CH + (K)*32 + oct1 * 8) * HW       \
                              + row_) * HW + ic_;                               \
      _Pragma("unroll") for (int j = 0; j < 8; ++j)                             \
        V[8 + j] = ok_ ? sp_[j * PLANE] : 0.0f;                                 \
    }                                                                           \
  }

  // ---- stage-write: pack + 2 x ds_write_b128 into wave buffer BUFOFF ----
#define SWRITE(V, SUB, BUFOFF)                                                  \
  {                                                                             \
    {                                                                           \
      union { ushort8_t s; unsigned u[4]; } pk_;                                \
      pk_.u[0] = pktrunc(V[0], V[1]);  pk_.u[1] = pktrunc(V[2], V[3]);          \
      pk_.u[2] = pktrunc(V[4], V[5]);  pk_.u[3] = pktrunc(V[6], V[7]);          \
      const int slot_ = oct0 ^ ((cu0 >> 1) & 3);                                \
      *reinterpret_cast<ushort8_t*>(wbase + (BUFOFF) + (SUB)*SUBB + cu0 * 64    \
                                    + slot_ * 16) = pk_.s;                      \
    }                                                                           \
    if (v1) {                                                                   \
      union { ushort8_t s; unsigned u[4]; } pk_;                                \
      pk_.u[0] = pktrunc(V[8], V[9]);   pk_.u[1] = pktrunc(V[10], V[11]);       \
      pk_.u[2] = pktrunc(V[12], V[13]); pk_.u[3] = pktrunc(V[14], V[15]);       \
      const int slot_ = oct1 ^ ((cu1 >> 1) & 3);                                \
      *reinterpret_cast<ushort8_t*>(wbase + (BUFOFF) + (SUB)*SUBB + cu1 * 64    \
                                    + slot_ * 16) = pk_.s;                      \
    }                                                                           \
  }

  // ---- compute one sub-row: 3 dx x { 8 A-frags, 2 B-frags, 16 MFMAs } ----
#define CSUB(SUB, BUFOFF, K)                                                    \
  _Pragma("unroll") for (int dx = 0; dx < 3; ++dx) {                            \
    const unsigned short* wp_ = Wb + ((SUB)*3 + dx) * (O_CH * I_CH)             \
                              + ln * I_CH + (K)*32 + lk4 * 8;                   \
    short8 a_[8];                                                               \
    _Pragma("unroll") for (int mt = 0; mt < 8; ++mt)                            \
      a_[mt] = *reinterpret_cast<const short8*>(wp_ + mt * 16 * I_CH);          \
    _Pragma("unroll") for (int nf = 0; nf < 2; ++nf) {                          \
      const int col_ = dx + nf * 16 + ln;                                       \
      const int slot_ = lk4 ^ ((col_ >> 1) & 3);                                \
      short8 bb_ = *reinterpret_cast<const short8*>(                            \
          wbase + (BUFOFF) + (SUB)*SUBB + col_ * 64 + slot_ * 16);              \
      _Pragma("unroll") for (int mt = 0; mt < 8; ++mt)                          \
        acc[mt][nf] = __builtin_amdgcn_mfma_f32_16x16x32_bf16(a_[mt], bb_,      \
                                                              acc[mt][nf], 0, 0, 0); \
    }                                                                           \
  }

  float LA[16], LB[16];

  // ---- prologue: stage chunk 0 into buf 0 (no barrier needed ever) ----
  SLOAD(LA, 0, 0) SWRITE(LA, 0, 0)
  SLOAD(LA, 0, 1) SWRITE(LA, 1, 0)
  SLOAD(LA, 0, 2) SWRITE(LA, 2, 0)

  // ---- main loop: 4 chunks of 32 ch, wave-private double-buffer, lag-1 ----
#pragma unroll
  for (int k = 0; k < 4; ++k) {
    const int rb = (k & 1) * WBUF;
    const int wb2 = ((k & 1) ^ 1) * WBUF;

    if (k < 3) SLOAD(LA, k + 1, 0)
    CSUB(0, rb, k)

    if (k < 3) SLOAD(LB, k + 1, 1)
    CSUB(1, rb, k)
    if (k < 3) SWRITE(LA, 0, wb2)

    if (k < 3) SLOAD(LA, k + 1, 2)
    CSUB(2, rb, k)
    if (k < 3) {
      SWRITE(LB, 1, wb2)
      SWRITE(LA, 2, wb2)
    }
  }

  // ---- epilogue: C/D map col=lane&15, row=(lane>>4)*4+j ----
  // wave covers cols [cb, cb+28): nf=0 -> ln 0..15, nf=1 -> ln 0..11
  float* outp = Out + (size_t)b * O_CH * PLANE + (size_t)y * HW + cb;
#pragma unroll
  for (int mt = 0; mt < 8; ++mt) {
#pragma unroll
    for (int j = 0; j < 4; ++j) {
      const int o = mt * 16 + lk4 * 4 + j;
      float* po = outp + (size_t)o * PLANE;
      po[ln] = acc[mt][0][j];
      if (ln < 12) po[16 + ln] = acc[mt][1][j];
    }
  }
}

extern "C" void kernel_launch(void* const* d_in, const int* in_sizes, int n_in,
                              void* d_out, int out_size, void* d_ws, size_t ws_size,
                              hipStream_t stream) {
  const float* x      = (const float*)d_in[0];
  const float* core   = (const float*)d_in[1];
  const float* periph = (const float*)d_in[2];
  const float* thr    = (const float*)d_in[3];
  const float* scale  = (const float*)d_in[4];
  unsigned short* Wb  = (unsigned short*)d_ws;   // 9*128*128*2 = 294,912 B

  wsynth_kernel<<<(O_CH * I_CH + 255) / 256, 256, 0, stream>>>(core, periph, thr, scale, Wb);

  const int grid = 32 * HW;   // one WG per (batch, output row) = 3584
  conv_wi<<<grid, 256, 0, stream>>>(x, Wb, (float*)d_out);
}

// Round 14
// 318.432 us; speedup vs baseline: 1.8437x; 1.8437x over previous
//
#include <hip/hip_runtime.h>

typedef short short8 __attribute__((ext_vector_type(8)));
typedef float f32x4 __attribute__((ext_vector_type(4)));
typedef unsigned short ushort8_t __attribute__((ext_vector_type(8)));

#define O_CH 128
#define I_CH 128
#define HW 112
#define PLANE (HW * HW)        // 12544
#define NCOL 114               // 112 cols + 2 halo
#define BUFB (3 * NCOL * 64)   // bytes per LDS buffer: 3 rows * 114 cols * 32ch * 2B

__device__ __forceinline__ unsigned short f2bf(float f) {
  union { float f; unsigned u; } v; v.f = f;
  unsigned r = v.u + 0x7FFFu + ((v.u >> 16) & 1u);   // RNE (weights only)
  return (unsigned short)(r >> 16);
}

// one-instruction truncate-pack: [lo,hi] floats -> packed bf16 pair
__device__ __forceinline__ unsigned pktrunc(float lo, float hi) {
  union { float f; unsigned u; } a, b; a.f = lo; b.f = hi;
  return __builtin_amdgcn_perm(b.u, a.u, 0x07060302u);
}

__global__ void wsynth_kernel(const float* __restrict__ core,
                              const float* __restrict__ periph,
                              const float* __restrict__ thr,
                              const float* __restrict__ scale,
                              unsigned short* __restrict__ Wb) {
  int idx = blockIdx.x * blockDim.x + threadIdx.x;   // o*128 + i
  if (idx >= O_CH * I_CH) return;
  int o = idx >> 7;
  float c = core[idx];
  float s = scale[0];
  float g = 1.0f / (1.0f + __expf(-s * (fabsf(c) - thr[o])));
#pragma unroll
  for (int tap = 0; tap < 9; ++tap) {
    float p  = (tap == 4) ? 1.0f : periph[tap < 4 ? tap : tap - 1];
    float gg = (tap == 4) ? 1.0f : g;
    Wb[tap * (O_CH * I_CH) + idx] = f2bf(c * p * gg);   // layout [tap][o][i]
  }
}

__global__ __launch_bounds__(256, 3)
void conv_kernel(const float* __restrict__ X,
                 const unsigned short* __restrict__ Wb,
                 float* __restrict__ Out) {
  // 2 buffers x [row 0..2][col 0..113][32 ch] bf16; col-row = 64 B = 4 slots of 16 B.
  // Slot swizzle (R9/R10-verified, 0 conflicts): slot' = chgrp ^ ((col>>1)&3)
  __shared__ unsigned short Xs[2 * 3 * NCOL * 32];   // 43,776 B -> 3 WGs/CU
  char* lds = (char*)Xs;

  // XCD-chunked swizzle: 3584 = 8 XCDs x 448 (R6-verified)
  const int bid = blockIdx.x;
  const int L = (bid & 7) * 448 + (bid >> 3);
  const int b = L / HW;
  const int y = L - b * HW;

  const int t   = threadIdx.x;
  const int wv  = t >> 6;              // wave 0..3
  const int l   = t & 63;
  const int ln  = l & 15;              // MFMA frag lane
  const int lk4 = l >> 4;              // k-slice 0..3
  const int mi  = wv >> 1;             // o-half: o in [mi*64, +64)
  const int ng  = wv & 1;              // col group: ng0 -> nf 0..3, ng1 -> nf 0..2
  const int cb  = ng * 64;             // column base for this wave

  // staging coords (R9-identical)
  const int c    = t & 127;            // staged col (input col + 1)
  const int chb  = (t >> 7) * 16;      // local channel base: 0 or 16
  const int icol = c - 1;
  const bool cok = (c < NCOL);
  const int wxor = (c >> 1) & 3;       // verified conflict-free write swizzle

  f32x4 acc[4][4];                     // [m-frag][nf]; ng1 leaves nf=3 unused
#pragma unroll
  for (int mt = 0; mt < 4; ++mt)
#pragma unroll
    for (int nf = 0; nf < 4; ++nf)
      acc[mt][nf] = (f32x4)0.0f;

  // per-wave weight base: 64 o's starting at mi*64
  const unsigned short* wbase = Wb + (mi * 64 + ln) * I_CH + lk4 * 8;

#define LOAD16(V, KCH, SUB)                                                     \
  {                                                                             \
    const int row_ = y + (SUB)-1;                                               \
    const bool ok_ = (row_ >= 0) && (row_ < HW) && (icol >= 0) && (icol < HW);  \
    const float* sp_ = X + ((size_t)(b * I_CH + (KCH) + chb) * HW + row_) * HW  \
                       + icol;                                                  \
    _Pragma("unroll") for (int j = 0; j < 16; ++j) V[j] = 0.0f;                 \
    if (ok_) {                                                                  \
      _Pragma("unroll") for (int j = 0; j < 16; ++j) V[j] = sp_[j * PLANE];     \
    }                                                                           \
  }

#define WRITE16(V, SUB, WB)                                                     \
  if (cok) {                                                                    \
    const int base_ = ((SUB)*NCOL + c) * 64;                                    \
    _Pragma("unroll") for (int q = 0; q < 2; ++q) {                             \
      union { ushort8_t s; unsigned u[4]; } pk_;                                \
      pk_.u[0] = pktrunc(V[q * 8 + 0], V[q * 8 + 1]);                           \
      pk_.u[1] = pktrunc(V[q * 8 + 2], V[q * 8 + 3]);                           \
      pk_.u[2] = pktrunc(V[q * 8 + 4], V[q * 8 + 5]);                           \
      pk_.u[3] = pktrunc(V[q * 8 + 6], V[q * 8 + 7]);                           \
      const int slot_ = ((chb >> 3) + q) ^ wxor;                                \
      *reinterpret_cast<ushort8_t*>((WB) + base_ + slot_ * 16) = pk_.s;         \
    }                                                                           \
  }

  // ALL 12 A-fragments for a sub-phase, issued BEFORE the staging loads so the
  // MFMA's vmcnt wait on A (~28 outstanding) never drains the staging queue
  // (the R10 bug: A after staging -> 3x full-latency drains per sub).
#define APLOADSUB(AF, SUB, K)                                                   \
  _Pragma("unroll") for (int dx = 0; dx < 3; ++dx) {                            \
    const unsigned short* wp_ = wbase + ((SUB)*3 + dx) * (O_CH * I_CH)          \
                              + (K)*32;                                         \
    AF[dx][0] = *reinterpret_cast<const short8*>(wp_);                          \
    AF[dx][1] = *reinterpret_cast<const short8*>(wp_ + 16 * I_CH);              \
    AF[dx][2] = *reinterpret_cast<const short8*>(wp_ + 32 * I_CH);              \
    AF[dx][3] = *reinterpret_cast<const short8*>(wp_ + 48 * I_CH);              \
  }

  // compute sub-phase: per dx 3-4 b128 B-reads, each feeding 4 MFMAs
#define COMPUTE_SUB2R(SUB, RB, AF)                                              \
  _Pragma("unroll") for (int dx = 0; dx < 3; ++dx) {                            \
    const int q_ = cb + dx + ln;                                                \
    const int rslot_ = lk4 ^ ((q_ >> 1) & 3);   /* 16-col stride: invariant */  \
    const char* bp_ = (RB) + ((SUB)*NCOL + q_) * 64 + rslot_ * 16;              \
    short8 b0_ = *reinterpret_cast<const short8*>(bp_);                         \
    short8 b1_ = *reinterpret_cast<const short8*>(bp_ + 1024);                  \
    short8 b2_ = *reinterpret_cast<const short8*>(bp_ + 2048);                  \
    acc[0][0] = __builtin_amdgcn_mfma_f32_16x16x32_bf16(AF[dx][0], b0_, acc[0][0], 0, 0, 0); \
    acc[1][0] = __builtin_amdgcn_mfma_f32_16x16x32_bf16(AF[dx][1], b0_, acc[1][0], 0, 0, 0); \
    acc[2][0] = __builtin_amdgcn_mfma_f32_16x16x32_bf16(AF[dx][2], b0_, acc[2][0], 0, 0, 0); \
    acc[3][0] = __builtin_amdgcn_mfma_f32_16x16x32_bf16(AF[dx][3], b0_, acc[3][0], 0, 0, 0); \
    acc[0][1] = __builtin_amdgcn_mfma_f32_16x16x32_bf16(AF[dx][0], b1_, acc[0][1], 0, 0, 0); \
    acc[1][1] = __builtin_amdgcn_mfma_f32_16x16x32_bf16(AF[dx][1], b1_, acc[1][1], 0, 0, 0); \
    acc[2][1] = __builtin_amdgcn_mfma_f32_16x16x32_bf16(AF[dx][2], b1_, acc[2][1], 0, 0, 0); \
    acc[3][1] = __builtin_amdgcn_mfma_f32_16x16x32_bf16(AF[dx][3], b1_, acc[3][1], 0, 0, 0); \
    acc[0][2] = __builtin_amdgcn_mfma_f32_16x16x32_bf16(AF[dx][0], b2_, acc[0][2], 0, 0, 0); \
    acc[1][2] = __builtin_amdgcn_mfma_f32_16x16x32_bf16(AF[dx][1], b2_, acc[1][2], 0, 0, 0); \
    acc[2][2] = __builtin_amdgcn_mfma_f32_16x16x32_bf16(AF[dx][2], b2_, acc[2][2], 0, 0, 0); \
    acc[3][2] = __builtin_amdgcn_mfma_f32_16x16x32_bf16(AF[dx][3], b2_, acc[3][2], 0, 0, 0); \
    if (ng == 0) {                                                              \
      short8 b3_ = *reinterpret_cast<const short8*>(bp_ + 3072);                \
      acc[0][3] = __builtin_amdgcn_mfma_f32_16x16x32_bf16(AF[dx][0], b3_, acc[0][3], 0, 0, 0); \
      acc[1][3] = __builtin_amdgcn_mfma_f32_16x16x32_bf16(AF[dx][1], b3_, acc[1][3], 0, 0, 0); \
      acc[2][3] = __builtin_amdgcn_mfma_f32_16x16x32_bf16(AF[dx][2], b3_, acc[2][3], 0, 0, 0); \
      acc[3][3] = __builtin_amdgcn_mfma_f32_16x16x32_bf16(AF[dx][3], b3_, acc[3][3], 0, 0, 0); \
    }                                                                           \
  }

  // ---- prologue: stage chunk 0 into buffer 0 ----
  {
    float P0[16], P1[16], P2[16];
    LOAD16(P0, 0, 0)
    LOAD16(P1, 0, 1)
    LOAD16(P2, 0, 2)
    WRITE16(P0, 0, lds)
    WRITE16(P1, 1, lds)
    WRITE16(P2, 2, lds)
  }
  __syncthreads();

  // ---- main loop: 4 chunks, double-buffered, lag-1 writes; per sub:
  //      A-loads FIRST, staging loads second, compute third (vmcnt discipline) ----
#pragma unroll
  for (int k = 0; k < 4; ++k) {
    char* rbuf = lds + (k & 1) * BUFB;
    char* wbuf = lds + ((k & 1) ^ 1) * BUFB;
    float LA[16], LB[16];
    short8 AF[3][4];

    // sub 0
    APLOADSUB(AF, 0, k)
    if (k < 3) LOAD16(LA, (k + 1) * 32, 0)
    COMPUTE_SUB2R(0, rbuf, AF)

    // sub 1 (write sub0's staged row after compute: lag-1)
    APLOADSUB(AF, 1, k)
    if (k < 3) LOAD16(LB, (k + 1) * 32, 1)
    COMPUTE_SUB2R(1, rbuf, AF)
    if (k < 3) WRITE16(LA, 0, wbuf)

    // sub 2
    APLOADSUB(AF, 2, k)
    if (k < 3) LOAD16(LA, (k + 1) * 32, 2)
    COMPUTE_SUB2R(2, rbuf, AF)
    if (k < 3) {
      WRITE16(LB, 1, wbuf)
      WRITE16(LA, 2, wbuf)
      __syncthreads();
    }
  }

  // ---- epilogue: wave (mi,ng) owns o [mi*64,+64) x cols [ng*64, +64/48) ----
  float* outp = Out + (size_t)b * O_CH * PLANE + (size_t)y * HW + cb;
#pragma unroll
  for (int mt = 0; mt < 4; ++mt) {
#pragma unroll
    for (int j = 0; j < 4; ++j) {
      const int o = mi * 64 + mt * 16 + lk4 * 4 + j;
      float* po = outp + (size_t)o * PLANE;
#pragma unroll
      for (int nf = 0; nf < 4; ++nf) {
        if (nf < 3 || ng == 0) {
          po[nf * 16 + ln] = acc[mt][nf][j];
        }
      }
    }
  }
}

extern "C" void kernel_launch(void* const* d_in, const int* in_sizes, int n_in,
                              void* d_out, int out_size, void* d_ws, size_t ws_size,
                              hipStream_t stream) {
  const float* x      = (const float*)d_in[0];
  const float* core   = (const float*)d_in[1];
  const float* periph = (const float*)d_in[2];
  const float* thr    = (const float*)d_in[3];
  const float* scale  = (const float*)d_in[4];
  unsigned short* Wb  = (unsigned short*)d_ws;   // 9*128*128*2 = 294,912 B

  wsynth_kernel<<<(O_CH * I_CH + 255) / 256, 256, 0, stream>>>(core, periph, thr, scale, Wb);

  const int grid = 32 * HW;   // one WG per (batch, output row) = 3584
  conv_kernel<<<grid, 256, 0, stream>>>(x, Wb, (float*)d_out);
}